// Round 1
// baseline (141.253 us; speedup 1.0000x reference)
//
#include <hip/hip_runtime.h>
#include <hip/hip_cooperative_groups.h>
#include <math.h>

namespace cg = cooperative_groups;

#define NPTS   131072
#define NB     32
#define HD     64
#define KCELL  112            // cells over (-10,10)
#define PARTS  16             // build parts per flow block (16*7 = 112 cells)
#define PARTN  7
#define LIMIT  10.0f
#define CLAMPV 10000.0f

// Build scratch and the eval table time-share the same LDS: the build phase
// is dead (its results are in global ws) before the table is staged in after
// the grid-wide barrier.
struct BuildScratch {
    float W2s[HD * HD];        // 16 KB
    float h1c[8 * HD];         // 2 KB
    float h2c[8 * 65];         // padded
    float w1s[HD], b1s[HD], b2s[HD], w3a[HD], w3b[HD];
    float sv[9], cv[9];        // 8 nodes per part
};

union SharedU {
    BuildScratch b;            // 21.9 KB
    float4 tab[NB * KCELL];    // 57.3 KB  -> union = 57.3 KB -> 2 WG/CU
};

// ---------- fused: build table (512 WGs x 7 cells), grid.sync, eval ----------
// Mask algebra (unchanged from verified kernel): the reference's second
// per-step mask check tests post-permute values that already passed check 1
// (|.|<10); dead lanes are unchanged, so check 2 == check 1 -> dropped. The
// pre-coupling CLAMP(+-1e4) is identity for live lanes -> dropped.
// Node MLP evaluation is instruction-identical to the previous build_tab, so
// the chord table in ws is bit-identical; only the final reduction order
// changes (4 atomics/WG -> LDS reduce + 1 atomic/WG).
__global__ __launch_bounds__(256) void realnvp_fused(
    const float* __restrict__ x,
    const float* __restrict__ W1, const float* __restrict__ b1,
    const float* __restrict__ W2, const float* __restrict__ b2,
    const float* __restrict__ W3, const float* __restrict__ b3,
    const float* __restrict__ loc, const float* __restrict__ log_scale,
    float* __restrict__ ws, float* __restrict__ out)
{
    __shared__ __align__(16) SharedU sh;
    __shared__ float red[4];

    const int tid = threadIdx.x;
    const int bid = blockIdx.x;

    // ---- prefetch eval inputs; hides under the build phase ----
    const int g = bid * 256 + tid;
    const float2 xv = ((const float2*)x)[g];
    const float l0 = loc[0], l1 = loc[1];
    const float ls0 = log_scale[0], ls1 = log_scale[1];

    if (bid == 0 && tid == 0) out[0] = 0.0f;   // ordered before atomics by grid.sync

    // ================= phase 1: build 7 cells of one block =================
    const int p = bid >> 4;                    // flow block
    const int r = bid & 15;                    // part
    const int nstart = r * PARTN;              // 0,7,...,105
    const float Hh = 20.0f / (float)KCELL;

    for (int i = tid; i < HD * HD; i += 256) sh.b.W2s[i] = W2[p * HD * HD + i];
    if (tid < HD) {
        sh.b.w1s[tid] = W1[p * HD + tid];
        sh.b.b1s[tid] = b1[p * HD + tid];
        sh.b.b2s[tid] = b2[p * HD + tid];
        sh.b.w3a[tid] = W3[p * 2 * HD + 2 * tid + 0];
        sh.b.w3b[tid] = W3[p * 2 * HD + 2 * tid + 1];
    }
    __syncthreads();

    // (a) layer-1 activations at this part's 8 nodes
    for (int task = tid; task < 8 * HD; task += 256) {
        const int n = task >> 6, k = task & 63;
        const float z = fmaf((float)(nstart + n), Hh, -10.0f);
        sh.b.h1c[task] = fmaxf(fmaf(sh.b.w1s[k], z, sh.b.b1s[k]), 0.0f);
    }
    __syncthreads();

    // (b) layer-2 preactivation (lanes j consecutive -> free 2-way banks)
    for (int task = tid; task < 8 * HD; task += 256) {
        const int n = task >> 6, j = task & 63;
        float acc = sh.b.b2s[j];
        const float* h1p = sh.b.h1c + (n << 6);
        #pragma unroll 8
        for (int k = 0; k < HD; ++k)
            acc = fmaf(sh.b.W2s[(k << 6) + j], h1p[k], acc);
        sh.b.h2c[n * 65 + j] = acc;
    }
    __syncthreads();

    // (c) output layer -> node (shift, scale)
    const float b30 = b3[p * 2 + 0], b31 = b3[p * 2 + 1];
    if (tid < 16) {
        const int n = tid >> 1, d = tid & 1;
        const float* w3p = d ? sh.b.w3b : sh.b.w3a;
        float acc = d ? b31 : b30;
        const float* h2p = sh.b.h2c + n * 65;
        #pragma unroll 8
        for (int j = 0; j < HD; ++j)
            acc = fmaf(fmaxf(h2p[j], 0.0f), w3p[j], acc);
        (d ? sh.b.cv : sh.b.sv)[n] = acc;
    }
    __syncthreads();

    // (d) per-cell chord coefficients: A=(s1-s0)/H, B=s0-A*z0  (== lerp)
    if (tid < PARTN) {
        const int c = nstart + tid;
        const float z0 = fmaf((float)c, Hh, -10.0f);
        const float A = (sh.b.sv[tid + 1] - sh.b.sv[tid]) / Hh;
        const float B = fmaf(-A, z0, sh.b.sv[tid]);
        const float C = (sh.b.cv[tid + 1] - sh.b.cv[tid]) / Hh;
        const float Dd = fmaf(-C, z0, sh.b.cv[tid]);
        ((float4*)ws)[p * KCELL + c] = make_float4(A, B, C, Dd);
    }

    // ============ grid-wide barrier: table complete and visible ============
    cg::this_grid().sync();

    // ================= phase 2: stage table to LDS, eval ===================
    {
        const uint4* g4 = (const uint4*)ws;            // 3584 uint4
        uint4* l4 = (uint4*)sh.tab;
        #pragma unroll
        for (int i = tid; i < NB * KCELL; i += 256) l4[i] = g4[i];
    }
    __syncthreads();

    const float INVH = (float)KCELL / 20.0f;
    float za = xv.x, zb = xv.y;
    float ld = 0.0f;
    bool mask = true;

    for (int t = 0; t < NB; ++t) {
        const int pp = NB - 1 - t;

        // single live test per step (see proof above)
        mask = mask && (fabsf(za) < LIMIT) && (fabsf(zb) < LIMIT);

        // permute (pure swap for live lanes; dead lanes keep old z)
        const float z1 = mask ? zb : za;
        const float z2 = mask ? za : zb;

        int u = (int)fmaf(z1, INVH, 10.0f * INVH);
        u = min(max(u, 0), KCELL - 1);

        const float4 abcd = sh.tab[pp * KCELL + u];
        const float shift = fmaf(abcd.x, z1, abcd.y);
        const float scale = fmaf(abcd.z, z1, abcd.w);
        const float z2n = (z2 - shift) * __expf(-scale);

        if (mask) {
            za = z1;                                   // |z1| < 10: clamp identity
            zb = fminf(fmaxf(z2n, -CLAMPV), CLAMPV);
            ld -= scale;
        }
    }

    const float e0 = __expf(-ls0), e1 = __expf(-ls1);
    const float t0 = (za - l0) * e0, t1 = (zb - l1) * e1;
    float val = -1.8378770664093453f - (ls0 + ls1)
                - 0.5f * (t0 * t0 + t1 * t1) + ld;

    // wave reduce -> cross-wave LDS reduce -> ONE atomic per WG (512 total)
    #pragma unroll
    for (int off = 32; off > 0; off >>= 1)
        val += __shfl_down(val, off, 64);
    if ((tid & 63) == 0) red[tid >> 6] = val;
    __syncthreads();
    if (tid == 0)
        atomicAdd(out, (red[0] + red[1]) + (red[2] + red[3]));
}

extern "C" void kernel_launch(void* const* d_in, const int* in_sizes, int n_in,
                              void* d_out, int out_size, void* d_ws, size_t ws_size,
                              hipStream_t stream) {
    const float* x   = (const float*)d_in[0];
    const float* W1  = (const float*)d_in[1];
    const float* b1  = (const float*)d_in[2];
    const float* W2  = (const float*)d_in[3];
    const float* b2  = (const float*)d_in[4];
    const float* W3  = (const float*)d_in[5];
    const float* b3  = (const float*)d_in[6];
    const float* loc = (const float*)d_in[7];
    const float* lsc = (const float*)d_in[8];
    float* out = (float*)d_out;
    float* ws  = (float*)d_ws;

    void* args[] = {
        (void*)&x, (void*)&W1, (void*)&b1, (void*)&W2, (void*)&b2,
        (void*)&W3, (void*)&b3, (void*)&loc, (void*)&lsc,
        (void*)&ws, (void*)&out
    };
    hipLaunchCooperativeKernel((void*)realnvp_fused,
                               dim3(NPTS / 256), dim3(256),
                               args, 0, stream);
}

// Round 3
// 88.013 us; speedup vs baseline: 1.6049x; 1.6049x over previous
//
#include <hip/hip_runtime.h>
#include <math.h>

#define NPTS   131072
#define NB     32
#define HD     64
#define KCELL  112            // cells over (-10,10)
#define PARTS  8              // build parts per flow block
#define PARTN  15             // cells per part (last part: 7)
#define LIMIT  10.0f
#define CLAMPV 10000.0f

// ws: float4 cellAB[NB][KCELL] = 57344 B  (A,B,C,D per cell)

// ---------- build: 256 WGs, each samples 16 nodes of one block's exact MLP ----------
// (verified bit-identical table; unchanged from the 109 µs kernel)
__global__ __launch_bounds__(256) void build_tab(
    const float* __restrict__ W1, const float* __restrict__ b1,
    const float* __restrict__ W2, const float* __restrict__ b2,
    const float* __restrict__ W3, const float* __restrict__ b3,
    float* __restrict__ ws, float* __restrict__ out)
{
    __shared__ __align__(16) float W2s[HD * HD];   // 16 KB
    __shared__ float h1c[16 * HD];                 // 4 KB
    __shared__ float h2c[16 * 65];                 // padded
    __shared__ float w1s[HD], b1s[HD], b2s[HD], w3a[HD], w3b[HD];
    __shared__ float sv[17], cv[17];               // node (shift, scale) values

    const int tid = threadIdx.x;
    const int p = blockIdx.x >> 3;                 // flow block
    const int r = blockIdx.x & 7;                  // part
    if (blockIdx.x == 0 && tid == 0) out[0] = 0.0f;

    const int nstart = r * PARTN;                  // first node
    const int ncell  = min(PARTN, KCELL - nstart); // cells emitted (15 or 7)
    const int nn     = ncell + 1;                  // nodes sampled (16 or 8)
    const float H    = 20.0f / (float)KCELL;

    for (int i = tid; i < HD * HD; i += 256) W2s[i] = W2[p * HD * HD + i];
    if (tid < HD) {
        w1s[tid] = W1[p * HD + tid];
        b1s[tid] = b1[p * HD + tid];
        b2s[tid] = b2[p * HD + tid];
        w3a[tid] = W3[p * 2 * HD + 2 * tid + 0];
        w3b[tid] = W3[p * 2 * HD + 2 * tid + 1];
    }
    __syncthreads();

    // (a) layer-1 activations at this part's nodes
    for (int task = tid; task < nn * HD; task += 256) {
        const int n = task >> 6, k = task & 63;
        const float z = fmaf((float)(nstart + n), H, -10.0f);
        h1c[task] = fmaxf(fmaf(w1s[k], z, b1s[k]), 0.0f);
    }
    __syncthreads();

    // (b) layer-2 preactivation (lanes j consecutive -> free 2-way banks)
    for (int task = tid; task < nn * HD; task += 256) {
        const int n = task >> 6, j = task & 63;
        float acc = b2s[j];
        const float* h1p = h1c + (n << 6);
        #pragma unroll 8
        for (int k = 0; k < HD; ++k)
            acc = fmaf(W2s[(k << 6) + j], h1p[k], acc);
        h2c[n * 65 + j] = acc;
    }
    __syncthreads();

    // (c) output layer -> node (shift, scale)
    const float b30 = b3[p * 2 + 0], b31 = b3[p * 2 + 1];
    if (tid < nn * 2) {
        const int n = tid >> 1, d = tid & 1;
        const float* w3p = d ? w3b : w3a;
        float acc = d ? b31 : b30;
        const float* h2p = h2c + n * 65;
        #pragma unroll 8
        for (int j = 0; j < HD; ++j)
            acc = fmaf(fmaxf(h2p[j], 0.0f), w3p[j], acc);
        (d ? cv : sv)[n] = acc;
    }
    __syncthreads();

    // (d) per-cell chord coefficients: A=(s1-s0)/H, B=s0-A*z0  (== lerp)
    if (tid < ncell) {
        const int c = nstart + tid;
        const float z0 = fmaf((float)c, H, -10.0f);
        const float A = (sv[tid + 1] - sv[tid]) / H;
        const float B = fmaf(-A, z0, sv[tid]);
        const float C = (cv[tid + 1] - cv[tid]) / H;
        const float D = fmaf(-C, z0, cv[tid]);
        ((float4*)ws)[p * KCELL + c] = make_float4(A, B, C, D);
    }
}

// ---------- eval: 2 points/thread (ILP=2), 256 WGs, 1 atomic/WG ----------
// Mask algebra (verified): the reference's second per-step mask check tests
// post-permute values that already passed check 1 (|.|<10); dead lanes are
// unchanged, so check 2 == check 1 -> dropped. Pre-coupling CLAMP(+-1e4) is
// identity for live lanes -> dropped. Bit-identical per-point math to the
// 109 µs kernel; only reduction tree and work partition change.
__global__ __launch_bounds__(256) void realnvp_eval(
    const float* __restrict__ x,
    const float* __restrict__ ws,
    const float* __restrict__ loc, const float* __restrict__ log_scale,
    float* __restrict__ out)
{
    __shared__ __align__(16) float4 tab[NB * KCELL];   // 57.3 KB
    __shared__ float red[4];

    const int tid = threadIdx.x;
    const int g = blockIdx.x * 256 + tid;              // float4 idx: pts 2g, 2g+1

    // issue the x load + scalars early; latency hides under table staging
    const float4 xv = ((const float4*)x)[g];
    const float l0 = loc[0], l1 = loc[1];
    const float ls0 = log_scale[0], ls1 = log_scale[1];

    {
        const uint4* g4 = (const uint4*)ws;            // 3584 uint4
        uint4* l4 = (uint4*)tab;
        #pragma unroll
        for (int i = tid; i < NB * KCELL; i += 256) l4[i] = g4[i];
    }
    __syncthreads();

    const float INVH = (float)KCELL / 20.0f;

    float za0 = xv.x, zb0 = xv.y;                      // chain 0 (point 2g)
    float za1 = xv.z, zb1 = xv.w;                      // chain 1 (point 2g+1)
    float ld0 = 0.0f, ld1 = 0.0f;
    bool m0 = true, m1 = true;

    for (int t = 0; t < NB; ++t) {
        const int p = NB - 1 - t;
        const float4* tp = tab + p * KCELL;

        // single live test per step (see proof above)
        m0 = m0 && (fabsf(za0) < LIMIT) && (fabsf(zb0) < LIMIT);
        m1 = m1 && (fabsf(za1) < LIMIT) && (fabsf(zb1) < LIMIT);

        // permute (pure swap for live lanes; dead lanes keep old z)
        const float z10 = m0 ? zb0 : za0;
        const float z20 = m0 ? za0 : zb0;
        const float z11 = m1 ? zb1 : za1;
        const float z21 = m1 ? za1 : zb1;

        int u0 = (int)fmaf(z10, INVH, 10.0f * INVH);
        int u1 = (int)fmaf(z11, INVH, 10.0f * INVH);
        u0 = min(max(u0, 0), KCELL - 1);
        u1 = min(max(u1, 0), KCELL - 1);

        const float4 c0 = tp[u0];                      // two independent ds_read_b128
        const float4 c1 = tp[u1];

        const float sh0 = fmaf(c0.x, z10, c0.y);
        const float sc0 = fmaf(c0.z, z10, c0.w);
        const float sh1 = fmaf(c1.x, z11, c1.y);
        const float sc1 = fmaf(c1.z, z11, c1.w);
        const float zn0 = (z20 - sh0) * __expf(-sc0);
        const float zn1 = (z21 - sh1) * __expf(-sc1);

        if (m0) { za0 = z10; zb0 = fminf(fmaxf(zn0, -CLAMPV), CLAMPV); ld0 -= sc0; }
        if (m1) { za1 = z11; zb1 = fminf(fmaxf(zn1, -CLAMPV), CLAMPV); ld1 -= sc1; }
    }

    const float e0 = __expf(-ls0), e1 = __expf(-ls1);
    const float t00 = (za0 - l0) * e0, t01 = (zb0 - l1) * e1;
    const float t10 = (za1 - l0) * e0, t11 = (zb1 - l1) * e1;
    float val = 2.0f * (-1.8378770664093453f - (ls0 + ls1))
                - 0.5f * (t00 * t00 + t01 * t01 + t10 * t10 + t11 * t11)
                + ld0 + ld1;

    // wave reduce -> cross-wave LDS reduce -> ONE atomic per WG (256 total)
    #pragma unroll
    for (int off = 32; off > 0; off >>= 1)
        val += __shfl_down(val, off, 64);
    if ((tid & 63) == 0) red[tid >> 6] = val;
    __syncthreads();
    if (tid == 0)
        atomicAdd(out, (red[0] + red[1]) + (red[2] + red[3]));
}

extern "C" void kernel_launch(void* const* d_in, const int* in_sizes, int n_in,
                              void* d_out, int out_size, void* d_ws, size_t ws_size,
                              hipStream_t stream) {
    const float* x   = (const float*)d_in[0];
    const float* W1  = (const float*)d_in[1];
    const float* b1  = (const float*)d_in[2];
    const float* W2  = (const float*)d_in[3];
    const float* b2  = (const float*)d_in[4];
    const float* W3  = (const float*)d_in[5];
    const float* b3  = (const float*)d_in[6];
    const float* loc = (const float*)d_in[7];
    const float* lsc = (const float*)d_in[8];
    float* out = (float*)d_out;
    float* ws  = (float*)d_ws;

    build_tab<<<NB * PARTS, 256, 0, stream>>>(W1, b1, W2, b2, W3, b3, ws, out);
    realnvp_eval<<<NPTS / 512, 256, 0, stream>>>(x, ws, loc, lsc, out);
}